// Round 4
// baseline (716.653 us; speedup 1.0000x reference)
//
#include <hip/hip_runtime.h>
#include <math.h>

#define T_TOK 32768
#define DIM   2048
#define E_N   64
#define KP    2048   // padded reduction length (col 0 of wpad is zero)
#define BR    32     // rows per block (4 waves x 8 rows)

// ws layout (floats): [0, 131072) wpad[64][2048]; [131072, +32768*64) logits
#define WS_WPAD_FLOATS (E_N * KP)

typedef float v4f __attribute__((ext_vector_type(4)));

// ---------------- kernel 0: shift/pad weight ----------------
__global__ __launch_bounds__(256) void k_padw(const float* __restrict__ w,
                                              float* __restrict__ wpad) {
  int idx = blockIdx.x * 256 + threadIdx.x;   // 0 .. 64*2048-1
  int e = idx >> 11;
  int c = idx & 2047;
  wpad[idx] = (c == 0) ? 0.f : w[e * 2047 + (c - 1)];
}

// ---------------- kernel 1: logits = x[:,1:] @ W^T ----------------
// No LDS, no barriers. W (512 KB) is L2-resident; the active k-slice stays
// in L1 (x loads are nontemporal so they don't evict it).
// block: 256 thr = 4 waves; wave owns 8 rows. lane = (eg<<2)|rg:
//   rows  = blk*32 + w*8 + rg*2 + {0,1}
//   experts = eg*4 + {0..3}   (4 consecutive lanes share eg -> W broadcast)
__global__ __launch_bounds__(256, 4) void k_logits(const float* __restrict__ x,
                                                   const float* __restrict__ wpad,
                                                   float* __restrict__ logits) {
  const int tid  = threadIdx.x;
  const int w    = tid >> 6;
  const int lane = tid & 63;
  const int rg   = lane & 3;
  const int eg   = lane >> 2;      // 0..15
  const int row0 = blockIdx.x * BR + w * 8 + rg * 2;

  const float* xr0 = x + (size_t)row0 * DIM;
  const float* xr1 = xr0 + DIM;
  const float* __restrict__ w0 = wpad + (size_t)(eg * 4 + 0) * KP;
  const float* __restrict__ w1 = wpad + (size_t)(eg * 4 + 1) * KP;
  const float* __restrict__ w2 = wpad + (size_t)(eg * 4 + 2) * KP;
  const float* __restrict__ w3 = wpad + (size_t)(eg * 4 + 3) * KP;

  float a0x = 0.f, a0y = 0.f, a0z = 0.f, a0w = 0.f;
  float a1x = 0.f, a1y = 0.f, a1z = 0.f, a1w = 0.f;

#pragma unroll 4
  for (int c4 = 0; c4 < DIM / 4; ++c4) {
    const int c = c4 * 4;
    const v4f x0 = __builtin_nontemporal_load((const v4f*)(xr0 + c));
    const v4f x1 = __builtin_nontemporal_load((const v4f*)(xr1 + c));
    const v4f v0 = *(const v4f*)(w0 + c);
    const v4f v1 = *(const v4f*)(w1 + c);
    const v4f v2 = *(const v4f*)(w2 + c);
    const v4f v3 = *(const v4f*)(w3 + c);

    a0x = fmaf(x0.x, v0.x, a0x); a0x = fmaf(x0.y, v0.y, a0x);
    a0x = fmaf(x0.z, v0.z, a0x); a0x = fmaf(x0.w, v0.w, a0x);
    a0y = fmaf(x0.x, v1.x, a0y); a0y = fmaf(x0.y, v1.y, a0y);
    a0y = fmaf(x0.z, v1.z, a0y); a0y = fmaf(x0.w, v1.w, a0y);
    a0z = fmaf(x0.x, v2.x, a0z); a0z = fmaf(x0.y, v2.y, a0z);
    a0z = fmaf(x0.z, v2.z, a0z); a0z = fmaf(x0.w, v2.w, a0z);
    a0w = fmaf(x0.x, v3.x, a0w); a0w = fmaf(x0.y, v3.y, a0w);
    a0w = fmaf(x0.z, v3.z, a0w); a0w = fmaf(x0.w, v3.w, a0w);

    a1x = fmaf(x1.x, v0.x, a1x); a1x = fmaf(x1.y, v0.y, a1x);
    a1x = fmaf(x1.z, v0.z, a1x); a1x = fmaf(x1.w, v0.w, a1x);
    a1y = fmaf(x1.x, v1.x, a1y); a1y = fmaf(x1.y, v1.y, a1y);
    a1y = fmaf(x1.z, v1.z, a1y); a1y = fmaf(x1.w, v1.w, a1y);
    a1z = fmaf(x1.x, v2.x, a1z); a1z = fmaf(x1.y, v2.y, a1z);
    a1z = fmaf(x1.z, v2.z, a1z); a1z = fmaf(x1.w, v2.w, a1z);
    a1w = fmaf(x1.x, v3.x, a1w); a1w = fmaf(x1.y, v3.y, a1w);
    a1w = fmaf(x1.z, v3.z, a1w); a1w = fmaf(x1.w, v3.w, a1w);
  }

  *(float4*)(logits + (size_t)row0 * E_N + eg * 4) = make_float4(a0x, a0y, a0z, a0w);
  *(float4*)(logits + (size_t)(row0 + 1) * E_N + eg * 4) = make_float4(a1x, a1y, a1z, a1w);
}

// ---------------- kernel 2: per-row group-limited top-k routing ----------------
__global__ __launch_bounds__(256) void k_route(const float* __restrict__ logits,
                                               const float* __restrict__ bias,
                                               float* __restrict__ out_w,
                                               float* __restrict__ out_i) {
  __shared__ float bl[E_N];
  if (threadIdx.x < E_N) bl[threadIdx.x] = bias[threadIdx.x];
  __syncthreads();

  const int row = blockIdx.x * 256 + threadIdx.x;      // grid sized exactly
  const float* lp = logits + (size_t)row * E_N;

  float sb[E_N];                                       // sigmoid(logit) + bias
#pragma unroll
  for (int e4 = 0; e4 < 16; ++e4) {
    float4 lv = *(const float4*)(lp + e4 * 4);
    sb[e4 * 4 + 0] = 1.f / (1.f + expf(-lv.x)) + bl[e4 * 4 + 0];
    sb[e4 * 4 + 1] = 1.f / (1.f + expf(-lv.y)) + bl[e4 * 4 + 1];
    sb[e4 * 4 + 2] = 1.f / (1.f + expf(-lv.z)) + bl[e4 * 4 + 2];
    sb[e4 * 4 + 3] = 1.f / (1.f + expf(-lv.w)) + bl[e4 * 4 + 3];
  }

  // group scores: sum of top-2 per group of 8
  float gs[8];
#pragma unroll
  for (int g = 0; g < 8; ++g) {
    float m1 = -__builtin_inff(), m2 = -__builtin_inff();
#pragma unroll
    for (int j = 0; j < 8; ++j) {
      float v = sb[g * 8 + j];
      if (v > m1) { m2 = m1; m1 = v; }
      else if (v > m2) { m2 = v; }
    }
    gs[g] = m1 + m2;
  }

  // top-4 groups (strict > : lower index wins ties, matches lax.top_k)
  unsigned gmask = 0;
#pragma unroll
  for (int tsel = 0; tsel < 4; ++tsel) {
    float best = -__builtin_inff(); int bi = 0;
#pragma unroll
    for (int g = 0; g < 8; ++g) {
      bool avail = ((gmask >> g) & 1u) == 0u;
      if (avail && gs[g] > best) { best = gs[g]; bi = g; }
    }
    gmask |= (1u << bi);
  }

  // taken-mask: pre-ban experts in dropped groups
  unsigned long long tm = 0ull;
#pragma unroll
  for (int g = 0; g < 8; ++g)
    if (((gmask >> g) & 1u) == 0u) tm |= (0xFFull << (8 * g));

  // top-8 experts over allowed groups
  float wv[8]; int io[8]; float wsum = 0.f;
#pragma unroll
  for (int tsel = 0; tsel < 8; ++tsel) {
    float best = -__builtin_inff(); int bi = 0;
#pragma unroll
    for (int e = 0; e < E_N; ++e) {
      bool avail = ((tm >> e) & 1ull) == 0ull;
      if (avail && sb[e] > best) { best = sb[e]; bi = e; }
    }
    tm |= (1ull << bi);
    float sv = best - bl[bi];        // original sigmoid score (bias removed)
    wv[tsel] = sv; io[tsel] = bi; wsum += sv;
  }

  const float scale = 2.5f / wsum;
  float4 w0 = make_float4(wv[0] * scale, wv[1] * scale, wv[2] * scale, wv[3] * scale);
  float4 w1 = make_float4(wv[4] * scale, wv[5] * scale, wv[6] * scale, wv[7] * scale);
  float4 i0 = make_float4((float)io[0], (float)io[1], (float)io[2], (float)io[3]);
  float4 i1 = make_float4((float)io[4], (float)io[5], (float)io[6], (float)io[7]);
  *(float4*)(out_w + (size_t)row * 8)     = w0;
  *(float4*)(out_w + (size_t)row * 8 + 4) = w1;
  *(float4*)(out_i + (size_t)row * 8)     = i0;
  *(float4*)(out_i + (size_t)row * 8 + 4) = i1;
}

extern "C" void kernel_launch(void* const* d_in, const int* in_sizes, int n_in,
                              void* d_out, int out_size, void* d_ws, size_t ws_size,
                              hipStream_t stream) {
  const float* x    = (const float*)d_in[0];
  const float* wgt  = (const float*)d_in[1];
  const float* bias = (const float*)d_in[2];
  float* out    = (float*)d_out;
  float* wpad   = (float*)d_ws;
  float* logits = (float*)d_ws + WS_WPAD_FLOATS;

  k_padw  <<<(E_N * KP) / 256, 256, 0, stream>>>(wgt, wpad);
  k_logits<<<T_TOK / BR,      256, 0, stream>>>(x, wpad, logits);
  k_route <<<T_TOK / 256,     256, 0, stream>>>(logits, bias,
                                                out, out + (size_t)T_TOK * 8);
}